// Round 9
// baseline (138.188 us; speedup 1.0000x reference)
//
#include <hip/hip_runtime.h>
#include <math.h>

typedef unsigned short u16;
typedef unsigned int u32;
typedef __attribute__((ext_vector_type(4))) float f32x4;
typedef __attribute__((ext_vector_type(8))) short s16x8;
typedef __attribute__((ext_vector_type(4))) unsigned short u16x4;

#define T_ 2048
#define C_ 1024

// fp32 -> bf16, round-half-up
__device__ __forceinline__ u16 f2b(float f) {
  u32 u = __builtin_bit_cast(u32, f);
  return (u16)((u + 0x8000u) >> 16);
}

__device__ __forceinline__ s16x8 pack8(float4 a, float4 b) {
  s16x8 r;
  r[0] = (short)f2b(a.x); r[1] = (short)f2b(a.y);
  r[2] = (short)f2b(a.z); r[3] = (short)f2b(a.w);
  r[4] = (short)f2b(b.x); r[5] = (short)f2b(b.y);
  r[6] = (short)f2b(b.z); r[7] = (short)f2b(b.w);
  return r;
}

// async global->LDS, 16B per lane; LDS dest = wave-uniform base + lane*16
__device__ __forceinline__ void gld_lds16(const void* g, void* l) {
  __builtin_amdgcn_global_load_lds(
      (const __attribute__((address_space(1))) u32*)g,
      (__attribute__((address_space(3))) u32*)l, 16, 0, 0);
}

// ---------------- kernel 0: weights fp32 [1024][64] x3 -> Wt bf16 [192][1024]
// transposed (k-contiguous). Softmax scale 1/8 AND log2(e) folded into W_q.
__global__ __launch_bounds__(256) void wconv(const float* __restrict__ Wq,
                                             const float* __restrict__ Wk,
                                             const float* __restrict__ Wv,
                                             u16* __restrict__ Wt) {
  __shared__ u16 t[64][68];
  const int bm = blockIdx.x >> 4;   // matrix 0..2
  const int kt = blockIdx.x & 15;   // k-tile of 64
  const float* src = (bm == 0) ? Wq : ((bm == 1) ? Wk : Wv);
  const float scale = (bm == 0) ? 0.18033688f : 1.0f;  // 0.125 * log2(e)
  const int krow = threadIdx.x >> 2;
  const int c0 = (threadIdx.x & 3) * 16;
  const float* sp = src + (size_t)(kt * 64 + krow) * 64 + c0;
#pragma unroll
  for (int i = 0; i < 4; ++i) {
    float4 v = *(const float4*)(sp + i * 4);
    t[c0 + i * 4 + 0][krow] = f2b(v.x * scale);
    t[c0 + i * 4 + 1][krow] = f2b(v.y * scale);
    t[c0 + i * 4 + 2][krow] = f2b(v.z * scale);
    t[c0 + i * 4 + 3][krow] = f2b(v.w * scale);
  }
  __syncthreads();
  const int n = threadIdx.x >> 2;
  const int koff = (threadIdx.x & 3) * 16;
  u16* dst = Wt + (size_t)(bm * 64 + n) * C_ + kt * 64 + koff;
#pragma unroll
  for (int i = 0; i < 4; ++i)
    *(u16x4*)(dst + i * 4) = *(const u16x4*)(&t[n][koff + i * 4]);
}

// ---------------- kernel 1: qkv projection — M=64, grid 256 (halves W
// re-staging 196->98 MB; TA-byte-bound per R6-R8 model). 512 thr = 8 waves
// = 4 m-groups x 2 n-halves. Both tiles double-buffered in exactly 64 KB:
// W via global_load_lds (2x24 KB), x via VGPR-load->bf16-pack->ds_write
// (2x8 KB bf16). ONE barrier per K-round; compute overlaps both stagings.
// XOR-swizzled chunk slots (key row&7) -> minimum-aliasing b128 LDS reads.
__global__ __launch_bounds__(512, 2) void proj(const float* __restrict__ x,
                                               const u16* __restrict__ Wt,
                                               u16* __restrict__ qo,
                                               u16* __restrict__ ko,
                                               u16* __restrict__ vt) {
  __shared__ __align__(16) u16 xs[2][64 * 64];    // 16 KB bf16 x tiles
  __shared__ __align__(16) u16 wsh[2][192 * 64];  // 48 KB bf16 W tiles
  const int tid = threadIdx.x;
  const int wave = tid >> 6, lane = tid & 63;
  const int quad = lane >> 4, l15 = lane & 15;
  const int mg = wave >> 1, nh = wave & 1;
  const int m0 = blockIdx.x * 64;

  // W staging roles: 3 calls/wave, call = 8 rows x 8 chunks(16B)
  const int rin = lane >> 3, slot = lane & 7;
  // x staging roles (thread-based): row, col-group of 8 floats
  const int xrow = tid >> 3, xcg = (tid & 7) * 8;
  const float* xp = x + (size_t)(m0 + xrow) * C_ + xcg;
  const int xslot = (tid & 7) ^ (xrow & 7);  // XOR'd chunk slot for ds_write

  auto stageW = [&](int kt, int buf) {
#pragma unroll
    for (int c = 0; c < 3; ++c) {
      const int row0 = 24 * wave + 8 * c;
      const int g = slot ^ rin;  // (row0+rin)&7 == rin
      gld_lds16(Wt + (size_t)(row0 + rin) * C_ + kt * 64 + g * 8,
                &wsh[buf][row0 * 64]);
    }
  };

  f32x4 acc[6];
#pragma unroll
  for (int j = 0; j < 6; ++j) acc[j] = {0.f, 0.f, 0.f, 0.f};

  // preload round 0
  stageW(0, 0);
  {
    float4 p0 = *(const float4*)(xp);
    float4 p1 = *(const float4*)(xp + 4);
    *(s16x8*)(&xs[0][xrow * 64 + xslot * 8]) = pack8(p0, p1);
  }
  __syncthreads();

  for (int kt = 0; kt < 16; ++kt) {
    const int buf = kt & 1;
    float4 p0, p1;
    if (kt < 15) {
      stageW(kt + 1, buf ^ 1);                  // async gld -> other buf
      p0 = *(const float4*)(xp + (kt + 1) * 64);  // x for next round
      p1 = *(const float4*)(xp + (kt + 1) * 64 + 4);
    }
    // ---- compute round kt (overlaps the staging above)
    s16x8 af[2];
    {
      const int r = 16 * mg + l15;
#pragma unroll
      for (int ks = 0; ks < 2; ++ks) {
        const int sl = (ks * 4 + quad) ^ (l15 & 7);
        af[ks] = *(const s16x8*)&xs[buf][r * 64 + sl * 8];
      }
    }
#pragma unroll
    for (int jj = 0; jj < 6; ++jj) {
      const int R = (nh * 6 + jj) * 16 + l15;
#pragma unroll
      for (int ks = 0; ks < 2; ++ks) {
        const int sl = (ks * 4 + quad) ^ (l15 & 7);
        s16x8 bf = *(const s16x8*)&wsh[buf][R * 64 + sl * 8];
        acc[jj] = __builtin_amdgcn_mfma_f32_16x16x32_bf16(af[ks], bf, acc[jj], 0, 0, 0);
      }
    }
    if (kt < 15)  // pack + write next x tile (waits only the 2 loads above)
      *(s16x8*)(&xs[buf ^ 1][xrow * 64 + xslot * 8]) = pack8(p0, p1);
    __syncthreads();  // drains W-gld + x ds_writes; frees buf for kt+2
  }

  // epilogue: C[m=x-row][n=W-row]; col=l15 (n), row=quad*4+i (m)
  const int r0 = m0 + 16 * mg + quad * 4;
#pragma unroll
  for (int jj = 0; jj < 6; ++jj) {
    const int ns = nh * 6 + jj;
    if (ns < 4) {
      const int col = ns * 16 + l15;
#pragma unroll
      for (int i = 0; i < 4; ++i)
        qo[(size_t)(r0 + i) * 64 + col] = f2b(acc[jj][i]);
    } else if (ns < 8) {
      const int col = (ns - 4) * 16 + l15;
#pragma unroll
      for (int i = 0; i < 4; ++i)
        ko[(size_t)(r0 + i) * 64 + col] = f2b(acc[jj][i]);
    } else {
      const int d = (ns - 8) * 16 + l15;
      const int bb = r0 >> 11, t0 = r0 & 2047;
      u16x4 pk = {f2b(acc[jj][0]), f2b(acc[jj][1]), f2b(acc[jj][2]), f2b(acc[jj][3])};
      *(u16x4*)(vt + (size_t)bb * (64 * T_) + (size_t)d * T_ + t0) = pk;
    }
  }
}

// ---------------- kernel 2: causal flash attention — Bq=64 + kv-SPLIT-2.
// Halves K/V re-staging vs Bq=32 (68 MB total); grid 512 = (qt 31..0 heavy-
// first) x (kv-half h) x (batch b). 4 waves = 4 q-groups (exclusive q-rows,
// NO in-block merge). K/V tiles LDS-staged (coalesced gld) double-buffered.
// Partials (fp32 O + m,l) -> ws; merged by the tiny kernel below.
__global__ __launch_bounds__(256, 2) void attn(const u16* __restrict__ qw,
                                               const u16* __restrict__ kw,
                                               const u16* __restrict__ vt,
                                               float* __restrict__ opart,
                                               float2* __restrict__ ml) {
  __shared__ __align__(16) u16 kvb[2][2][4096];  // [buf][K/V][64x64]
  __shared__ __align__(16) u16 Pb[4][16 * 72];   // per-wave P
  const int tid = threadIdx.x;
  const int wave = tid >> 6, lane = tid & 63;
  const int quad = lane >> 4, l15 = lane & 15;
  const int b = blockIdx.x & 7;
  const int h = (blockIdx.x >> 3) & 1;
  const int qt = 31 - (blockIdx.x >> 4);  // heavy q-tiles dispatch first

  const u16* qp = qw + ((size_t)b * T_ + qt * 64 + 16 * wave) * 64;
  const u16* kb = kw + (size_t)b * T_ * 64;
  const u16* vb = vt + (size_t)b * 64 * T_;

  const int n = qt + 1, c = (n + 1) >> 1;
  const int j0 = h ? c : 0, j1 = h ? n : c;

  s16x8 qf[2];  // Q as B-operand: q-row = l15 (wave-local), k = ks*32+quad*8+i
#pragma unroll
  for (int ks = 0; ks < 2; ++ks)
    qf[ks] = *(const s16x8*)(qp + l15 * 64 + ks * 32 + quad * 8);

  f32x4 o[4];
#pragma unroll
  for (int m = 0; m < 4; ++m) o[m] = {0.f, 0.f, 0.f, 0.f};
  float mr = -1e30f, lr = 0.0f;

  const int rin = lane >> 3, slot = lane & 7;
  const int g8 = slot ^ rin;
  u16* P = Pb[wave];

  auto stage = [&](int j, int buf) {
    if (wave < 2) {  // K tile rows
#pragma unroll
      for (int cc = 0; cc < 4; ++cc) {
        const int r0 = 32 * wave + 8 * cc;
        gld_lds16(kb + (size_t)(64 * j + r0 + rin) * 64 + g8 * 8,
                  &kvb[buf][0][r0 * 64]);
      }
    } else {  // V^T rows (d)
#pragma unroll
      for (int cc = 0; cc < 4; ++cc) {
        const int r0 = 32 * (wave - 2) + 8 * cc;
        gld_lds16(vb + (size_t)(r0 + rin) * T_ + 64 * j + g8 * 8,
                  &kvb[buf][1][r0 * 64]);
      }
    }
  };

  if (j0 < j1) {
    stage(j0, 0);
    __syncthreads();
    for (int j = j0; j < j1; ++j) {
      const int buf = (j - j0) & 1;
      if (j + 1 < j1) stage(j + 1, buf ^ 1);
      const u16* Kt = kvb[buf][0];
      const u16* Vt = kvb[buf][1];
      f32x4 s[4];
#pragma unroll
      for (int m = 0; m < 4; ++m) s[m] = {0.f, 0.f, 0.f, 0.f};
#pragma unroll
      for (int ks = 0; ks < 2; ++ks)
#pragma unroll
        for (int m = 0; m < 4; ++m) {
          const int row = 16 * m + l15;
          const int sl = (ks * 4 + quad) ^ (l15 & 7);
          s16x8 kf = *(const s16x8*)&Kt[row * 64 + sl * 8];
          s[m] = __builtin_amdgcn_mfma_f32_16x16x32_bf16(kf, qf[ks], s[m], 0, 0, 0);
        }
      if (j == qt) {  // diagonal: local kv 16m+quad*4+i vs local q 16*wave+l15
#pragma unroll
        for (int m = 0; m < 4; ++m)
#pragma unroll
          for (int i = 0; i < 4; ++i)
            if (16 * m + quad * 4 + i > 16 * wave + l15) s[m][i] = -INFINITY;
      }
      float mt = s[0][0];
#pragma unroll
      for (int m = 0; m < 4; ++m)
#pragma unroll
        for (int i = 0; i < 4; ++i) mt = fmaxf(mt, s[m][i]);
      mt = fmaxf(mt, __shfl_xor(mt, 16));
      mt = fmaxf(mt, __shfl_xor(mt, 32));
      const float mn = fmaxf(mr, mt);
      const float al = exp2f(mr - mn);
      mr = mn;
      float rs = 0.0f;
#pragma unroll
      for (int m = 0; m < 4; ++m)
#pragma unroll
        for (int i = 0; i < 4; ++i) {
          float p = exp2f(s[m][i] - mn);
          s[m][i] = p;
          rs += p;
        }
      rs += __shfl_xor(rs, 16);
      rs += __shfl_xor(rs, 32);
      lr = lr * al + rs;
#pragma unroll
      for (int m = 0; m < 4; ++m) {
        u16x4 pk = {f2b(s[m][0]), f2b(s[m][1]), f2b(s[m][2]), f2b(s[m][3])};
        *(u16x4*)(&P[l15 * 72 + 16 * m + quad * 4]) = pk;
      }
#pragma unroll
      for (int m = 0; m < 4; ++m) o[m] *= al;
#pragma unroll
      for (int ks = 0; ks < 2; ++ks) {
        s16x8 pf = *(const s16x8*)(&P[l15 * 72 + ks * 32 + quad * 8]);
#pragma unroll
        for (int m = 0; m < 4; ++m) {
          const int row = 16 * m + l15;
          const int sl = (ks * 4 + quad) ^ (l15 & 7);
          s16x8 vf = *(const s16x8*)&Vt[row * 64 + sl * 8];
          o[m] = __builtin_amdgcn_mfma_f32_16x16x32_bf16(vf, pf, o[m], 0, 0, 0);
        }
      }
      __syncthreads();
    }
  }
  // write fp32 partial: O[qloc][d], plus (m,l) per q-row
  const int pidx = ((b * 32 + qt) * 2 + h);
  float* OP = opart + (size_t)pidx * 4096;
  const int qloc = 16 * wave + l15;
#pragma unroll
  for (int m = 0; m < 4; ++m)
    *(f32x4*)(&OP[qloc * 64 + 16 * m + quad * 4]) = o[m];
  if (quad == 0) ml[pidx * 64 + qloc] = {mr, lr};
}

// ---------------- kernel 3: merge the 2 kv-half partials per (b, qt, row)
__global__ __launch_bounds__(256) void merge(const float* __restrict__ opart,
                                             const float2* __restrict__ ml,
                                             float* __restrict__ out) {
  const int blk = blockIdx.x;  // b*32 + qt
  const int b = blk >> 5, qt = blk & 31;
  const int t = threadIdx.x;
  const int r = t >> 2, cg = (t & 3) * 16;
  const float2 ml0 = ml[(blk * 2 + 0) * 64 + r];
  const float2 ml1 = ml[(blk * 2 + 1) * 64 + r];
  const float mstar = fmaxf(ml0.x, ml1.x);
  const float f0 = exp2f(ml0.x - mstar), f1 = exp2f(ml1.x - mstar);
  const float inv = 1.0f / (f0 * ml0.y + f1 * ml1.y);
  const float* O0 = opart + (size_t)(blk * 2 + 0) * 4096 + r * 64 + cg;
  const float* O1 = opart + (size_t)(blk * 2 + 1) * 4096 + r * 64 + cg;
  float* op = out + ((size_t)b * T_ + qt * 64 + r) * 64 + cg;
#pragma unroll
  for (int e = 0; e < 16; e += 4) {
    f32x4 a = *(const f32x4*)(O0 + e);
    f32x4 bb = *(const f32x4*)(O1 + e);
    f32x4 rv = (a * f0 + bb * f1) * inv;
    *(f32x4*)(op + e) = rv;
  }
}

extern "C" void kernel_launch(void* const* d_in, const int* in_sizes, int n_in,
                              void* d_out, int out_size, void* d_ws, size_t ws_size,
                              hipStream_t stream) {
  const float* x  = (const float*)d_in[0];
  const float* Wq = (const float*)d_in[1];
  const float* Wk = (const float*)d_in[2];
  const float* Wv = (const float*)d_in[3];
  float* out = (float*)d_out;
  char* ws = (char*)d_ws;
  u16* Wt = (u16*)ws;                                   // 384 KB
  u16* q  = (u16*)(ws + 393216);                        // 2 MB
  u16* k  = (u16*)(ws + 2490368);                       // 2 MB
  u16* vT = (u16*)(ws + 4587520);                       // 2 MB
  float*  OP = (float*)(ws + 6684672);                  // 8 MB partials
  float2* ML = (float2*)(ws + 15073280);                // 256 KB m,l
  hipLaunchKernelGGL(wconv, dim3(48), dim3(256), 0, stream, Wq, Wk, Wv, Wt);
  hipLaunchKernelGGL(proj, dim3(256), dim3(512), 0, stream, x, Wt, q, k, vT);
  hipLaunchKernelGGL(attn, dim3(512), dim3(256), 0, stream, q, k, vT, OP, ML);
  hipLaunchKernelGGL(merge, dim3(256), dim3(256), 0, stream, OP, ML, out);
}

// Round 10
// 137.491 us; speedup vs baseline: 1.0051x; 1.0051x over previous
//
#include <hip/hip_runtime.h>
#include <math.h>

typedef unsigned short u16;
typedef unsigned int u32;
typedef __attribute__((ext_vector_type(4))) float f32x4;
typedef __attribute__((ext_vector_type(8))) short s16x8;
typedef __attribute__((ext_vector_type(4))) unsigned short u16x4;

#define T_ 2048
#define C_ 1024

// fp32 -> bf16, round-half-up
__device__ __forceinline__ u16 f2b(float f) {
  u32 u = __builtin_bit_cast(u32, f);
  return (u16)((u + 0x8000u) >> 16);
}

__device__ __forceinline__ s16x8 pack8(float4 a, float4 b) {
  s16x8 r;
  r[0] = (short)f2b(a.x); r[1] = (short)f2b(a.y);
  r[2] = (short)f2b(a.z); r[3] = (short)f2b(a.w);
  r[4] = (short)f2b(b.x); r[5] = (short)f2b(b.y);
  r[6] = (short)f2b(b.z); r[7] = (short)f2b(b.w);
  return r;
}

// async global->LDS, 16B per lane; LDS dest = wave-uniform base + lane*16
__device__ __forceinline__ void gld_lds16(const void* g, void* l) {
  __builtin_amdgcn_global_load_lds(
      (const __attribute__((address_space(1))) u32*)g,
      (__attribute__((address_space(3))) u32*)l, 16, 0, 0);
}

// ---------------- kernel 0: weights fp32 [1024][64] x3 -> Wt bf16 [192][1024]
// transposed (k-contiguous). Softmax scale 1/8 AND log2(e) folded into W_q.
__global__ __launch_bounds__(256) void wconv(const float* __restrict__ Wq,
                                             const float* __restrict__ Wk,
                                             const float* __restrict__ Wv,
                                             u16* __restrict__ Wt) {
  __shared__ u16 t[64][68];
  const int bm = blockIdx.x >> 4;   // matrix 0..2
  const int kt = blockIdx.x & 15;   // k-tile of 64
  const float* src = (bm == 0) ? Wq : ((bm == 1) ? Wk : Wv);
  const float scale = (bm == 0) ? 0.18033688f : 1.0f;  // 0.125 * log2(e)
  const int krow = threadIdx.x >> 2;
  const int c0 = (threadIdx.x & 3) * 16;
  const float* sp = src + (size_t)(kt * 64 + krow) * 64 + c0;
#pragma unroll
  for (int i = 0; i < 4; ++i) {
    float4 v = *(const float4*)(sp + i * 4);
    t[c0 + i * 4 + 0][krow] = f2b(v.x * scale);
    t[c0 + i * 4 + 1][krow] = f2b(v.y * scale);
    t[c0 + i * 4 + 2][krow] = f2b(v.z * scale);
    t[c0 + i * 4 + 3][krow] = f2b(v.w * scale);
  }
  __syncthreads();
  const int n = threadIdx.x >> 2;
  const int koff = (threadIdx.x & 3) * 16;
  u16* dst = Wt + (size_t)(bm * 64 + n) * C_ + kt * 64 + koff;
#pragma unroll
  for (int i = 0; i < 4; ++i)
    *(u16x4*)(dst + i * 4) = *(const u16x4*)(&t[n][koff + i * 4]);
}

// ---------------- kernel 1: qkv projection — R9 version (M=64, grid 256;
// W staged 98 MB vs R8's 196). 512 thr = 8 waves = 4 m-groups x 2 n-halves.
// W dbuf via global_load_lds (2x24 KB), x dbuf via VGPR->bf16->ds_write
// (2x8 KB). One barrier/round. XOR-swizzled chunk slots.
__global__ __launch_bounds__(512, 2) void proj(const float* __restrict__ x,
                                               const u16* __restrict__ Wt,
                                               u16* __restrict__ qo,
                                               u16* __restrict__ ko,
                                               u16* __restrict__ vt) {
  __shared__ __align__(16) u16 xs[2][64 * 64];    // 16 KB bf16 x tiles
  __shared__ __align__(16) u16 wsh[2][192 * 64];  // 48 KB bf16 W tiles
  const int tid = threadIdx.x;
  const int wave = tid >> 6, lane = tid & 63;
  const int quad = lane >> 4, l15 = lane & 15;
  const int mg = wave >> 1, nh = wave & 1;
  const int m0 = blockIdx.x * 64;

  const int rin = lane >> 3, slot = lane & 7;
  const int xrow = tid >> 3, xcg = (tid & 7) * 8;
  const float* xp = x + (size_t)(m0 + xrow) * C_ + xcg;
  const int xslot = (tid & 7) ^ (xrow & 7);

  auto stageW = [&](int kt, int buf) {
#pragma unroll
    for (int c = 0; c < 3; ++c) {
      const int row0 = 24 * wave + 8 * c;
      const int g = slot ^ rin;
      gld_lds16(Wt + (size_t)(row0 + rin) * C_ + kt * 64 + g * 8,
                &wsh[buf][row0 * 64]);
    }
  };

  f32x4 acc[6];
#pragma unroll
  for (int j = 0; j < 6; ++j) acc[j] = {0.f, 0.f, 0.f, 0.f};

  stageW(0, 0);
  {
    float4 p0 = *(const float4*)(xp);
    float4 p1 = *(const float4*)(xp + 4);
    *(s16x8*)(&xs[0][xrow * 64 + xslot * 8]) = pack8(p0, p1);
  }
  __syncthreads();

  for (int kt = 0; kt < 16; ++kt) {
    const int buf = kt & 1;
    float4 p0, p1;
    if (kt < 15) {
      stageW(kt + 1, buf ^ 1);
      p0 = *(const float4*)(xp + (kt + 1) * 64);
      p1 = *(const float4*)(xp + (kt + 1) * 64 + 4);
    }
    s16x8 af[2];
    {
      const int r = 16 * mg + l15;
#pragma unroll
      for (int ks = 0; ks < 2; ++ks) {
        const int sl = (ks * 4 + quad) ^ (l15 & 7);
        af[ks] = *(const s16x8*)&xs[buf][r * 64 + sl * 8];
      }
    }
#pragma unroll
    for (int jj = 0; jj < 6; ++jj) {
      const int R = (nh * 6 + jj) * 16 + l15;
#pragma unroll
      for (int ks = 0; ks < 2; ++ks) {
        const int sl = (ks * 4 + quad) ^ (l15 & 7);
        s16x8 bf = *(const s16x8*)&wsh[buf][R * 64 + sl * 8];
        acc[jj] = __builtin_amdgcn_mfma_f32_16x16x32_bf16(af[ks], bf, acc[jj], 0, 0, 0);
      }
    }
    if (kt < 15)
      *(s16x8*)(&xs[buf ^ 1][xrow * 64 + xslot * 8]) = pack8(p0, p1);
    __syncthreads();
  }

  const int r0 = m0 + 16 * mg + quad * 4;
#pragma unroll
  for (int jj = 0; jj < 6; ++jj) {
    const int ns = nh * 6 + jj;
    if (ns < 4) {
      const int col = ns * 16 + l15;
#pragma unroll
      for (int i = 0; i < 4; ++i)
        qo[(size_t)(r0 + i) * 64 + col] = f2b(acc[jj][i]);
    } else if (ns < 8) {
      const int col = (ns - 4) * 16 + l15;
#pragma unroll
      for (int i = 0; i < 4; ++i)
        ko[(size_t)(r0 + i) * 64 + col] = f2b(acc[jj][i]);
    } else {
      const int d = (ns - 8) * 16 + l15;
      const int bb = r0 >> 11, t0 = r0 & 2047;
      u16x4 pk = {f2b(acc[jj][0]), f2b(acc[jj][1]), f2b(acc[jj][2]), f2b(acc[jj][3])};
      *(u16x4*)(vt + (size_t)bb * (64 * T_) + (size_t)d * T_ + t0) = pk;
    }
  }
}

// ---------------- kernel 2: causal flash attention — EXACT R8 version
// (known-good ~27 us): Bq=32, grid 512 (2 blocks/CU), b=blk&7, qt heavy-
// first; 4 waves = 2 q-groups x 2 kv-parity; LDS-staged K/V double-buffered;
// in-block 2-way merge. No partials, no extra kernel.
__global__ __launch_bounds__(256, 2) void attn(const u16* __restrict__ qw,
                                               const u16* __restrict__ kw,
                                               const u16* __restrict__ vt,
                                               float* __restrict__ out) {
  __shared__ __align__(16) u16 kvb[2][2][2][4096];  // [buf][tile][K/V][64x64]
  __shared__ __align__(16) u16 Ob[4][16 * 72];      // per-wave P; reused for O
  __shared__ float mbuf[4][16];
  __shared__ float lbuf[4][16];
  const int tid = threadIdx.x;
  const int wave = tid >> 6, lane = tid & 63;
  const int quad = lane >> 4, l15 = lane & 15;
  const int qg = wave >> 1, kg = wave & 1;
  const int b = blockIdx.x & 7;
  const int qt = 63 - (blockIdx.x >> 3);  // heavy q-tiles first

  const u16* qp = qw + ((size_t)b * T_ + qt * 32 + 16 * qg) * 64;
  const u16* kb = kw + (size_t)b * T_ * 64;
  const u16* vb = vt + (size_t)b * 64 * T_;

  const int jd = qt >> 1;           // last 64-wide kv tile
  const int R = (jd + 2) >> 1;      // rounds = ceil((jd+1)/2)

  s16x8 qf[2];  // Q as B-operand: q-row n = l15, k = ks*32+quad*8+i
#pragma unroll
  for (int ks = 0; ks < 2; ++ks)
    qf[ks] = *(const s16x8*)(qp + l15 * 64 + ks * 32 + quad * 8);

  f32x4 o[4];  // O^T acc: subtile m over d, col = q = l15
#pragma unroll
  for (int m = 0; m < 4; ++m) o[m] = {0.f, 0.f, 0.f, 0.f};
  float mr = -INFINITY, lr = 0.0f;

  u16* P = Ob[wave];

  const int rin = lane >> 3, slot = lane & 7;
  const int g8 = slot ^ rin;

  auto stage = [&](int r) {
    const int j = 2 * r + (wave >> 1);
    if (j > jd) return;
    u16* dst = kvb[r & 1][wave >> 1][wave & 1];
    if ((wave & 1) == 0) {
#pragma unroll
      for (int c = 0; c < 8; ++c)
        gld_lds16(kb + (size_t)(64 * j + 8 * c + rin) * 64 + g8 * 8,
                  dst + c * 512);
    } else {
#pragma unroll
      for (int c = 0; c < 8; ++c)
        gld_lds16(vb + (size_t)(8 * c + rin) * T_ + 64 * j + g8 * 8,
                  dst + c * 512);
    }
  };

  stage(0);
  __syncthreads();

  for (int r = 0; r < R; ++r) {
    if (r + 1 < R) stage(r + 1);
    const int j = 2 * r + kg;
    if (j <= jd) {
      const u16* Kt = kvb[r & 1][kg][0];
      const u16* Vt = kvb[r & 1][kg][1];
      f32x4 s[4];
#pragma unroll
      for (int m = 0; m < 4; ++m) s[m] = {0.f, 0.f, 0.f, 0.f};
#pragma unroll
      for (int ks = 0; ks < 2; ++ks)
#pragma unroll
        for (int m = 0; m < 4; ++m) {
          const int row = 16 * m + l15;
          const int sl = (ks * 4 + quad) ^ (row & 7);
          s16x8 kf = *(const s16x8*)&Kt[row * 64 + sl * 8];
          s[m] = __builtin_amdgcn_mfma_f32_16x16x32_bf16(kf, qf[ks], s[m], 0, 0, 0);
        }
      if (j == jd) {
#pragma unroll
        for (int m = 0; m < 4; ++m)
#pragma unroll
          for (int i = 0; i < 4; ++i)
            if (64 * jd + 16 * m + quad * 4 + i > 32 * qt + 16 * qg + l15)
              s[m][i] = -INFINITY;
      }
      float mt = s[0][0];
#pragma unroll
      for (int m = 0; m < 4; ++m)
#pragma unroll
        for (int i = 0; i < 4; ++i) mt = fmaxf(mt, s[m][i]);
      mt = fmaxf(mt, __shfl_xor(mt, 16));
      mt = fmaxf(mt, __shfl_xor(mt, 32));
      const float mn = fmaxf(mr, mt);
      const float al = exp2f(mr - mn);
      mr = mn;
      float rs = 0.0f;
#pragma unroll
      for (int m = 0; m < 4; ++m)
#pragma unroll
        for (int i = 0; i < 4; ++i) {
          float p = exp2f(s[m][i] - mn);
          s[m][i] = p;
          rs += p;
        }
      rs += __shfl_xor(rs, 16);
      rs += __shfl_xor(rs, 32);
      lr = lr * al + rs;
#pragma unroll
      for (int m = 0; m < 4; ++m) {
        u16x4 pk = {f2b(s[m][0]), f2b(s[m][1]), f2b(s[m][2]), f2b(s[m][3])};
        *(u16x4*)(&P[l15 * 72 + 16 * m + quad * 4]) = pk;
      }
#pragma unroll
      for (int m = 0; m < 4; ++m) o[m] *= al;
#pragma unroll
      for (int ks = 0; ks < 2; ++ks) {
        s16x8 pf = *(const s16x8*)(&P[l15 * 72 + ks * 32 + quad * 8]);
#pragma unroll
        for (int m = 0; m < 4; ++m) {
          const int row = 16 * m + l15;
          const int sl = (ks * 4 + quad) ^ (row & 7);
          s16x8 vf = *(const s16x8*)&Vt[row * 64 + sl * 8];
          o[m] = __builtin_amdgcn_mfma_f32_16x16x32_bf16(vf, pf, o[m], 0, 0, 0);
        }
      }
    }
    __syncthreads();
  }

  if (quad == 0) {
    mbuf[wave][l15] = mr;
    lbuf[wave][l15] = lr;
  }
#pragma unroll
  for (int m = 0; m < 4; ++m) {
    u16x4 pk = {f2b(o[m][0]), f2b(o[m][1]), f2b(o[m][2]), f2b(o[m][3])};
    *(u16x4*)(&Ob[wave][l15 * 72 + 16 * m + quad * 4]) = pk;
  }
  __syncthreads();
  const int rr = tid >> 3;          // 0..31
  const int cg = (tid & 7) * 8;     // 0..56
  const int qgr = rr >> 4, r16 = rr & 15;
  const float m0 = mbuf[qgr * 2][r16], m1 = mbuf[qgr * 2 + 1][r16];
  const float mstar = fmaxf(m0, m1);
  const float f0 = exp2f(m0 - mstar), f1 = exp2f(m1 - mstar);
  const float lsum = f0 * lbuf[qgr * 2][r16] + f1 * lbuf[qgr * 2 + 1][r16];
  const float inv = 1.0f / lsum;
  s16x8 o0 = *(const s16x8*)(&Ob[qgr * 2][r16 * 72 + cg]);
  s16x8 o1 = *(const s16x8*)(&Ob[qgr * 2 + 1][r16 * 72 + cg]);
  float av[8];
#pragma unroll
  for (int e = 0; e < 8; ++e) {
    float x0 = __builtin_bit_cast(float, ((u32)(u16)o0[e]) << 16);
    float x1 = __builtin_bit_cast(float, ((u32)(u16)o1[e]) << 16);
    av[e] = (f0 * x0 + f1 * x1) * inv;
  }
  float* op = out + ((size_t)b * T_ + qt * 32 + rr) * 64 + cg;
  float4 st0 = {av[0], av[1], av[2], av[3]};
  float4 st1 = {av[4], av[5], av[6], av[7]};
  *(float4*)(op + 0) = st0;
  *(float4*)(op + 4) = st1;
}

extern "C" void kernel_launch(void* const* d_in, const int* in_sizes, int n_in,
                              void* d_out, int out_size, void* d_ws, size_t ws_size,
                              hipStream_t stream) {
  const float* x  = (const float*)d_in[0];
  const float* Wq = (const float*)d_in[1];
  const float* Wk = (const float*)d_in[2];
  const float* Wv = (const float*)d_in[3];
  float* out = (float*)d_out;
  char* ws = (char*)d_ws;
  u16* Wt = (u16*)ws;                                   // 384 KB
  u16* q  = (u16*)(ws + 393216);                        // 2 MB
  u16* k  = (u16*)(ws + 2490368);                       // 2 MB
  u16* vT = (u16*)(ws + 4587520);                       // 2 MB
  hipLaunchKernelGGL(wconv, dim3(48), dim3(256), 0, stream, Wq, Wk, Wv, Wt);
  hipLaunchKernelGGL(proj, dim3(256), dim3(512), 0, stream, x, Wt, q, k, vT);
  hipLaunchKernelGGL(attn, dim3(512), dim3(256), 0, stream, q, k, vT, out);
}